// Round 2
// baseline (409.051 us; speedup 1.0000x reference)
//
#include <hip/hip_runtime.h>
#include <stdint.h>

#define B_DIM 8
#define L_DIM 512
#define D_DIM 1024
#define S_DIM 6144
#define M_DIM (B_DIM * S_DIM)   // 49152
#define NCHUNK 8
#define CHUNK (L_DIM / NCHUNK)  // 64

typedef __attribute__((ext_vector_type(8))) short short8;
typedef __attribute__((ext_vector_type(4))) float f32x4;
typedef __attribute__((ext_vector_type(8))) unsigned short us8;

// round-to-nearest-even fp32 -> bf16 bits
__device__ __forceinline__ unsigned short f2bf(float f) {
    unsigned int u = __float_as_uint(f);
    u += 0x7FFFu + ((u >> 16) & 1u);
    return (unsigned short)(u >> 16);
}

// ---------------- Phase 1a: per-chunk sums of h over L ----------------
// thread id -> (b, c, d); csum[b][c][d] = sum_{l in chunk c} h[b][l][d]
__global__ __launch_bounds__(256) void chunk_sums(const float* __restrict__ h,
                                                  float* __restrict__ csum) {
    int tid = blockIdx.x * 256 + threadIdx.x;   // 65536 total
    int d = tid & 1023;
    int c = (tid >> 10) & 7;
    int b = tid >> 13;
    const float* hp = h + ((size_t)b * L_DIM + c * CHUNK) * D_DIM + d;
    float s = 0.f;
    #pragma unroll 8
    for (int i = 0; i < CHUNK; ++i) s += hp[(size_t)i * D_DIM];
    csum[tid] = s;
}

// ---------------- Phase 1b: build cs[b][l][d] (exclusive prefix, L+1 rows) ----
__global__ __launch_bounds__(256) void build_cs(const float* __restrict__ h,
                                                const float* __restrict__ csum,
                                                float* __restrict__ cs) {
    int tid = blockIdx.x * 256 + threadIdx.x;   // 65536 total
    int d = tid & 1023;
    int c = (tid >> 10) & 7;
    int b = tid >> 13;
    float p = 0.f;
    for (int cc = 0; cc < c; ++cc)              // wave-uniform loop (c uniform per block)
        p += csum[(b << 13) + (cc << 10) + d];
    const float* hp = h + ((size_t)b * L_DIM + c * CHUNK) * D_DIM + d;
    float* cp = cs + ((size_t)b * (L_DIM + 1) + c * CHUNK) * D_DIM + d;
    if (c == 0) cp[0] = 0.f;
    #pragma unroll 8
    for (int i = 0; i < CHUNK; ++i) {
        p += hp[(size_t)i * D_DIM];
        cp[(size_t)(i + 1) * D_DIM] = p;
    }
}

// ---------------- Phase 2: span_rep -> bf16 ----------------
// thread handles 8 consecutive d of one (b,s)
__global__ __launch_bounds__(256) void spanrep(const float* __restrict__ cs,
                                               const int* __restrict__ span_idx,
                                               unsigned short* __restrict__ rep) {
    int tid = blockIdx.x * 256 + threadIdx.x;   // 6,291,456 total
    int d8 = tid & 127;
    int bs = tid >> 7;                           // 0..49151
    int b = bs / S_DIM;
    int2 se = ((const int2*)span_idx)[bs];
    int st = min(max(se.x, 0), L_DIM - 1);
    int en = min(max(se.y, 0), L_DIM - 1);
    bool valid = st <= en;
    float inv = valid ? 1.0f / (float)(en - st + 1) : 0.0f;
    const float* base = cs + (size_t)b * (L_DIM + 1) * D_DIM + d8 * 8;
    const float4* pe = (const float4*)(base + (size_t)(en + 1) * D_DIM);
    const float4* ps = (const float4*)(base + (size_t)st * D_DIM);
    float4 e0 = pe[0], e1 = pe[1];
    float4 s0 = ps[0], s1 = ps[1];
    us8 o;
    o[0] = f2bf((e0.x - s0.x) * inv);
    o[1] = f2bf((e0.y - s0.y) * inv);
    o[2] = f2bf((e0.z - s0.z) * inv);
    o[3] = f2bf((e0.w - s0.w) * inv);
    o[4] = f2bf((e1.x - s1.x) * inv);
    o[5] = f2bf((e1.y - s1.y) * inv);
    o[6] = f2bf((e1.z - s1.z) * inv);
    o[7] = f2bf((e1.w - s1.w) * inv);
    *(us8*)&rep[(size_t)bs * D_DIM + d8 * 8] = o;
}

// ---------------- Phase 3: W -> bf16 ----------------
__global__ __launch_bounds__(256) void wconv(const float* __restrict__ W,
                                             unsigned short* __restrict__ Wbf) {
    int tid = blockIdx.x * 256 + threadIdx.x;   // 131072 total
    const float4* p = (const float4*)(W + (size_t)tid * 8);
    float4 a = p[0], c = p[1];
    us8 o;
    o[0] = f2bf(a.x); o[1] = f2bf(a.y); o[2] = f2bf(a.z); o[3] = f2bf(a.w);
    o[4] = f2bf(c.x); o[5] = f2bf(c.y); o[6] = f2bf(c.z); o[7] = f2bf(c.w);
    *(us8*)&Wbf[(size_t)tid * 8] = o;
}

// ---------------- Phase 4: GEMM (M=49152, N=1024, K=1024), bias+ReLU ------
// A: [M,K] bf16 bits (rep), Wt: [N,K] bf16 bits, out fp32 [M,N]
__global__ __launch_bounds__(256) void gemm_bias_relu(
    const unsigned short* __restrict__ A,
    const unsigned short* __restrict__ Wt,
    const float* __restrict__ bias,
    float* __restrict__ out) {
    constexpr int K = D_DIM, N = D_DIM;
    __shared__ __align__(16) unsigned short As[128 * 64];
    __shared__ __align__(16) unsigned short Bs[128 * 64];
    const int tid = threadIdx.x;
    const int wid = tid >> 6, lane = tid & 63;
    const int bn = blockIdx.x & 7;          // 8 column tiles
    const int bm = blockIdx.x >> 3;         // 384 row tiles
    const int wr = wid >> 1, wc = wid & 1;
    const int rowA = bm * 128;
    const int rowB = bn * 128;

    f32x4 acc[4][4];
    #pragma unroll
    for (int i = 0; i < 4; ++i)
        #pragma unroll
        for (int j = 0; j < 4; ++j) acc[i][j] = (f32x4){0.f, 0.f, 0.f, 0.f};

    for (int k0 = 0; k0 < K; k0 += 64) {
        // stage A and B tiles (128x64 bf16 each) via direct-to-LDS 16B loads
        #pragma unroll
        for (int inst = 0; inst < 4; ++inst) {
            int e = inst * 2048 + tid * 8;  // element offset in tile
            int r = e >> 6, c = e & 63;
            const unsigned short* srcA = A + (size_t)(rowA + r) * K + (k0 + c);
            const unsigned short* srcB = Wt + (size_t)(rowB + r) * K + (k0 + c);
            __builtin_amdgcn_global_load_lds(
                (const __attribute__((address_space(1))) void*)srcA,
                (__attribute__((address_space(3))) void*)&As[inst * 2048 + wid * 512],
                16, 0, 0);
            __builtin_amdgcn_global_load_lds(
                (const __attribute__((address_space(1))) void*)srcB,
                (__attribute__((address_space(3))) void*)&Bs[inst * 2048 + wid * 512],
                16, 0, 0);
        }
        asm volatile("s_waitcnt vmcnt(0)" ::: "memory");
        __syncthreads();

        #pragma unroll
        for (int ks = 0; ks < 2; ++ks) {
            const int kc = ks * 32 + (lane >> 4) * 8;
            short8 af[4], bf[4];
            #pragma unroll
            for (int i = 0; i < 4; ++i) {
                af[i] = *(const short8*)&As[(wr * 64 + i * 16 + (lane & 15)) * 64 + kc];
                bf[i] = *(const short8*)&Bs[(wc * 64 + i * 16 + (lane & 15)) * 64 + kc];
            }
            #pragma unroll
            for (int i = 0; i < 4; ++i)
                #pragma unroll
                for (int j = 0; j < 4; ++j)
                    acc[i][j] = __builtin_amdgcn_mfma_f32_16x16x32_bf16(
                        af[i], bf[j], acc[i][j], 0, 0, 0);
        }
        __syncthreads();
    }

    // epilogue: C/D layout col=lane&15, row=(lane>>4)*4+r  (guide m89/m91)
    const int m0 = rowA + wr * 64;
    const int n0 = rowB + wc * 64;
    const int rq = lane >> 4;
    const int cl = lane & 15;
    float bv[4];
    #pragma unroll
    for (int j = 0; j < 4; ++j) bv[j] = bias[n0 + j * 16 + cl];
    #pragma unroll
    for (int i = 0; i < 4; ++i)
        #pragma unroll
        for (int j = 0; j < 4; ++j)
            #pragma unroll
            for (int r = 0; r < 4; ++r) {
                int m = m0 + i * 16 + rq * 4 + r;
                int n = n0 + j * 16 + cl;
                float v = acc[i][j][r] + bv[j];
                out[(size_t)m * N + n] = v > 0.f ? v : 0.f;
            }
}

extern "C" void kernel_launch(void* const* d_in, const int* in_sizes, int n_in,
                              void* d_out, int out_size, void* d_ws, size_t ws_size,
                              hipStream_t stream) {
    const float* h = (const float*)d_in[0];
    const int* span = (const int*)d_in[1];
    const float* W = (const float*)d_in[2];
    const float* bias = (const float*)d_in[3];
    float* out = (float*)d_out;

    char* ws = (char*)d_ws;
    // ws layout (bytes):
    //   cs   : [B][L+1][D] fp32 = 16,809,984    @ 0
    //   Wbf  : [D][D]     bf16 =  2,097,152     @ 16,809,984
    //   csum : [B][8][D]  fp32 =    262,144     @ 18,907,136
    //   rep  : [M][D]     bf16 = 100,663,296    @ 19,169,280
    float* cs = (float*)(ws);
    unsigned short* Wbf = (unsigned short*)(ws + 16809984);
    float* csum = (float*)(ws + 18907136);
    unsigned short* rep = (unsigned short*)(ws + 19169280);

    chunk_sums<<<256, 256, 0, stream>>>(h, csum);
    build_cs<<<256, 256, 0, stream>>>(h, csum, cs);
    wconv<<<512, 256, 0, stream>>>(W, Wbf);
    spanrep<<<24576, 256, 0, stream>>>(cs, span, rep);
    gemm_bias_relu<<<3072, 256, 0, stream>>>(rep, Wbf, bias, out);
}

// Round 3
// 383.267 us; speedup vs baseline: 1.0673x; 1.0673x over previous
//
#include <hip/hip_runtime.h>
#include <hip/hip_bf16.h>
#include <stdint.h>

#define B_DIM 8
#define L_DIM 512
#define D_DIM 1024
#define S_DIM 6144
#define NCHUNK 8
#define CHUNK (L_DIM / NCHUNK)      // 64
#define CSB (513 * 1024)            // floats per batch in cs ([L+1][D])

typedef __attribute__((ext_vector_type(8))) short short8;
typedef __attribute__((ext_vector_type(4))) float f32x4;
typedef __attribute__((ext_vector_type(8))) unsigned short us8;

__device__ __forceinline__ unsigned short bf16b(float x) {
    __hip_bfloat16 h = __float2bfloat16(x);
    return *reinterpret_cast<unsigned short*>(&h);
}

// round-to-nearest-even fp32 -> bf16 bits (used by wconv; same rounding as cvt)
__device__ __forceinline__ unsigned short f2bf(float f) {
    unsigned int u = __float_as_uint(f);
    u += 0x7FFFu + ((u >> 16) & 1u);
    return (unsigned short)(u >> 16);
}

// ---------------- Phase 1a: per-chunk sums of h over L ----------------
__global__ __launch_bounds__(256) void chunk_sums(const float* __restrict__ h,
                                                  float* __restrict__ csum) {
    int tid = blockIdx.x * 256 + threadIdx.x;   // 65536 total
    int d = tid & 1023;
    int c = (tid >> 10) & 7;
    int b = tid >> 13;
    const float* hp = h + ((size_t)b * L_DIM + c * CHUNK) * D_DIM + d;
    float s = 0.f;
    #pragma unroll 8
    for (int i = 0; i < CHUNK; ++i) s += hp[(size_t)i * D_DIM];
    csum[tid] = s;
}

// ---------------- Phase 1b: build cs[b][l][d] (exclusive prefix, L+1 rows) ----
__global__ __launch_bounds__(256) void build_cs(const float* __restrict__ h,
                                                const float* __restrict__ csum,
                                                float* __restrict__ cs) {
    int tid = blockIdx.x * 256 + threadIdx.x;   // 65536 total
    int d = tid & 1023;
    int c = (tid >> 10) & 7;
    int b = tid >> 13;
    float p = 0.f;
    for (int cc = 0; cc < c; ++cc)
        p += csum[(b << 13) + (cc << 10) + d];
    const float* hp = h + ((size_t)b * L_DIM + c * CHUNK) * D_DIM + d;
    float* cp = cs + ((size_t)b * (L_DIM + 1) + c * CHUNK) * D_DIM + d;
    if (c == 0) cp[0] = 0.f;
    #pragma unroll 8
    for (int i = 0; i < CHUNK; ++i) {
        p += hp[(size_t)i * D_DIM];
        cp[(size_t)(i + 1) * D_DIM] = p;
    }
}

// ---------------- Phase 2: W -> bf16 ----------------
__global__ __launch_bounds__(256) void wconv(const float* __restrict__ W,
                                             unsigned short* __restrict__ Wbf) {
    int tid = blockIdx.x * 256 + threadIdx.x;   // 131072 total
    const float4* p = (const float4*)(W + (size_t)tid * 8);
    float4 a = p[0], c = p[1];
    us8 o;
    o[0] = f2bf(a.x); o[1] = f2bf(a.y); o[2] = f2bf(a.z); o[3] = f2bf(a.w);
    o[4] = f2bf(c.x); o[5] = f2bf(c.y); o[6] = f2bf(c.z); o[7] = f2bf(c.w);
    *(us8*)&Wbf[(size_t)tid * 8] = o;
}

// ---------------- Phase 3: fused span-gather + GEMM + bias + ReLU ----------
// grid 1536 = 384 bm x 4 bn; 512 threads = 8 waves (2 x 4); tile 128x256, BK=64.
// A built on the fly from cs (L2-resident) with XOR-swizzled LDS; B staged via
// global_load_lds with pre-swizzled source (same involution).
__global__ __launch_bounds__(512, 2) void fused_gemm(
    const float* __restrict__ cs,
    const int* __restrict__ span_idx,
    const unsigned short* __restrict__ Wbf,
    const float* __restrict__ bias,
    float* __restrict__ out) {
    constexpr int K = D_DIM, N = D_DIM;
    __shared__ __align__(16) unsigned short As[2][128 * 64];
    __shared__ __align__(16) unsigned short Bs[2][256 * 64];
    __shared__ int sOffS[128];
    __shared__ int sOffE[128];
    __shared__ float sInv[128];

    const int tid = threadIdx.x;
    const int wid = tid >> 6, lane = tid & 63;
    const int widbase = wid << 6;

    // XCD-aware bijective swizzle: 1536 blocks, 192 per XCD
    int blk = blockIdx.x;
    int swz = (blk & 7) * 192 + (blk >> 3);
    const int bm = swz >> 2;                  // 0..383
    const int bn = swz & 3;                   // 0..3
    const int rowM = bm * 128;
    const int colN = bn * 256;
    const int b = bm / 48;                    // 6144/128 = 48 tiles per batch
    const float* csb = cs + (size_t)b * CSB;

    // span metadata for this block's 128 rows
    if (tid < 128) {
        int2 se = ((const int2*)span_idx)[rowM + tid];
        int st = min(max(se.x, 0), L_DIM - 1);
        int en = min(max(se.y, 0), L_DIM - 1);
        float inv = (st <= en) ? 1.0f / (float)(en - st + 1) : 0.0f;
        sOffS[tid] = st << 10;                // *D
        sOffE[tid] = (en + 1) << 10;
        sInv[tid] = inv;
    }
    __syncthreads();

    // per-thread A-build assignment: rows ar0 and ar0+64, col-chunk ac8 (8 floats)
    const int ar0 = tid >> 3;                 // 0..63
    const int ac8 = tid & 7;                  // 0..7
    const float* pS0 = csb + sOffS[ar0] + ac8 * 8;
    const float* pE0 = csb + sOffE[ar0] + ac8 * 8;
    const float inv0 = sInv[ar0];
    const float* pS1 = csb + sOffS[ar0 + 64] + ac8 * 8;
    const float* pE1 = csb + sOffE[ar0 + 64] + ac8 * 8;
    const float inv1 = sInv[ar0 + 64];
    // swizzled LDS write offsets (bytes): byte = r*128 + ((c8*16) ^ ((r&7)<<4))
    const int wa0 = ar0 * 128 + ((ac8 * 16) ^ ((ar0 & 7) << 4));
    const int wa1 = (ar0 + 64) * 128 + ((ac8 * 16) ^ ((ar0 & 7) << 4));

    const int fr = lane & 15;
    const int kq = lane >> 4;
    const int wr = wid >> 2, wc = wid & 3;

    f32x4 acc[4][4];
    #pragma unroll
    for (int i = 0; i < 4; ++i)
        #pragma unroll
        for (int j = 0; j < 4; ++j) acc[i][j] = (f32x4){0.f, 0.f, 0.f, 0.f};

    float4 eA0, eA1, sA0, sA1, eB0, eB1, sB0, sB1;

#define CS_LOAD(k0v) do { \
        eA0 = *(const float4*)(pE0 + (k0v));     eA1 = *(const float4*)(pE0 + (k0v) + 4); \
        sA0 = *(const float4*)(pS0 + (k0v));     sA1 = *(const float4*)(pS0 + (k0v) + 4); \
        eB0 = *(const float4*)(pE1 + (k0v));     eB1 = *(const float4*)(pE1 + (k0v) + 4); \
        sB0 = *(const float4*)(pS1 + (k0v));     sB1 = *(const float4*)(pS1 + (k0v) + 4); \
    } while (0)

#define A_WRITE(bufi) do { \
        us8 o0, o1; \
        o0[0] = bf16b((eA0.x - sA0.x) * inv0); o0[1] = bf16b((eA0.y - sA0.y) * inv0); \
        o0[2] = bf16b((eA0.z - sA0.z) * inv0); o0[3] = bf16b((eA0.w - sA0.w) * inv0); \
        o0[4] = bf16b((eA1.x - sA1.x) * inv0); o0[5] = bf16b((eA1.y - sA1.y) * inv0); \
        o0[6] = bf16b((eA1.z - sA1.z) * inv0); o0[7] = bf16b((eA1.w - sA1.w) * inv0); \
        o1[0] = bf16b((eB0.x - sB0.x) * inv1); o1[1] = bf16b((eB0.y - sB0.y) * inv1); \
        o1[2] = bf16b((eB0.z - sB0.z) * inv1); o1[3] = bf16b((eB0.w - sB0.w) * inv1); \
        o1[4] = bf16b((eB1.x - sB1.x) * inv1); o1[5] = bf16b((eB1.y - sB1.y) * inv1); \
        o1[6] = bf16b((eB1.z - sB1.z) * inv1); o1[7] = bf16b((eB1.w - sB1.w) * inv1); \
        *(us8*)((char*)As[bufi] + wa0) = o0; \
        *(us8*)((char*)As[bufi] + wa1) = o1; \
    } while (0)

#define STAGE_B(k0v, bufi) do { \
        _Pragma("unroll") \
        for (int i = 0; i < 4; ++i) { \
            int ci = i * 512 + tid; \
            int rB = ci >> 3, cB = ci & 7; \
            const unsigned short* srcB = Wbf + (size_t)(colN + rB) * K + (k0v) + ((cB ^ (rB & 7)) * 8); \
            __builtin_amdgcn_global_load_lds( \
                (const __attribute__((address_space(1))) void*)srcB, \
                (__attribute__((address_space(3))) void*)&Bs[bufi][(i * 512 + widbase) * 8], \
                16, 0, 0); \
        } \
    } while (0)

#define COMPUTE(bufi) do { \
        _Pragma("unroll") \
        for (int ks = 0; ks < 2; ++ks) { \
            const int kb = ks * 64 + kq * 16; \
            short8 af[4], bq[4]; \
            _Pragma("unroll") \
            for (int i = 0; i < 4; ++i) { \
                int ra = wr * 64 + i * 16 + fr; \
                af[i] = *(const short8*)((const char*)As[bufi] + ra * 128 + (kb ^ ((ra & 7) << 4))); \
                int rb = wc * 64 + i * 16 + fr; \
                bq[i] = *(const short8*)((const char*)Bs[bufi] + rb * 128 + (kb ^ ((rb & 7) << 4))); \
            } \
            _Pragma("unroll") \
            for (int i = 0; i < 4; ++i) \
                _Pragma("unroll") \
                for (int j = 0; j < 4; ++j) \
                    acc[i][j] = __builtin_amdgcn_mfma_f32_16x16x32_bf16(af[i], bq[j], acc[i][j], 0, 0, 0); \
        } \
    } while (0)

    // prologue: stage tile 0
    STAGE_B(0, 0);
    CS_LOAD(0);
    A_WRITE(0);
    __syncthreads();

    int buf = 0;
    for (int t = 0; t < 16; ++t) {
        if (t < 15) {
            STAGE_B((t + 1) * 64, buf ^ 1);   // B(t+1) in flight during compute
            CS_LOAD((t + 1) * 64);            // cs gather in flight during compute
        }
        COMPUTE(buf);
        if (t < 15) A_WRITE(buf ^ 1);         // loads have landed; convert+write
        __syncthreads();                      // drains vmcnt+lgkm; next tile ready
        buf ^= 1;
    }

    // epilogue: C/D layout col=lane&15, row=(lane>>4)*4+r  (m89/m91)
    const int m0 = rowM + wr * 64;
    const int n0 = colN + wc * 64;
    float bv[4];
    #pragma unroll
    for (int j = 0; j < 4; ++j) bv[j] = bias[n0 + j * 16 + fr];
    #pragma unroll
    for (int i = 0; i < 4; ++i)
        #pragma unroll
        for (int j = 0; j < 4; ++j)
            #pragma unroll
            for (int r = 0; r < 4; ++r) {
                int m = m0 + i * 16 + kq * 4 + r;
                int n = n0 + j * 16 + fr;
                float v = acc[i][j][r] + bv[j];
                out[(size_t)m * N + n] = v > 0.f ? v : 0.f;
            }
#undef CS_LOAD
#undef A_WRITE
#undef STAGE_B
#undef COMPUTE
}

extern "C" void kernel_launch(void* const* d_in, const int* in_sizes, int n_in,
                              void* d_out, int out_size, void* d_ws, size_t ws_size,
                              hipStream_t stream) {
    const float* h = (const float*)d_in[0];
    const int* span = (const int*)d_in[1];
    const float* W = (const float*)d_in[2];
    const float* bias = (const float*)d_in[3];
    float* out = (float*)d_out;

    char* ws = (char*)d_ws;
    // ws layout (bytes):
    //   cs   : [B][L+1][D] fp32 = 16,809,984  @ 0
    //   Wbf  : [D][D]     bf16 =  2,097,152   @ 16,809,984
    //   csum : [B][8][D]  fp32 =    262,144   @ 18,907,136
    float* cs = (float*)(ws);
    unsigned short* Wbf = (unsigned short*)(ws + 16809984);
    float* csum = (float*)(ws + 18907136);

    chunk_sums<<<256, 256, 0, stream>>>(h, csum);
    build_cs<<<256, 256, 0, stream>>>(h, csum, cs);
    wconv<<<512, 256, 0, stream>>>(W, Wbf);
    fused_gemm<<<1536, 512, 0, stream>>>(cs, span, Wbf, bias, out);
}

// Round 5
// 381.576 us; speedup vs baseline: 1.0720x; 1.0044x over previous
//
#include <hip/hip_runtime.h>
#include <hip/hip_bf16.h>
#include <stdint.h>

#define B_DIM 8
#define L_DIM 512
#define D_DIM 1024
#define S_DIM 6144
#define NCHUNK 8
#define CHUNK (L_DIM / NCHUNK)      // 64
#define CSB (513 * 1024)            // floats per batch in cs ([L+1][D])

typedef __attribute__((ext_vector_type(8))) short short8;
typedef __attribute__((ext_vector_type(4))) float f32x4;
typedef __attribute__((ext_vector_type(8))) unsigned short us8;

__device__ __forceinline__ unsigned short bf16b(float x) {
    __hip_bfloat16 h = __float2bfloat16(x);
    return *reinterpret_cast<unsigned short*>(&h);
}

__device__ __forceinline__ unsigned short f2bf(float f) {
    unsigned int u = __float_as_uint(f);
    u += 0x7FFFu + ((u >> 16) & 1u);
    return (unsigned short)(u >> 16);
}

// ---------------- Phase 1a: per-chunk sums of h over L ----------------
__global__ __launch_bounds__(256) void chunk_sums(const float* __restrict__ h,
                                                  float* __restrict__ csum) {
    int tid = blockIdx.x * 256 + threadIdx.x;   // 65536 total
    int d = tid & 1023;
    int c = (tid >> 10) & 7;
    int b = tid >> 13;
    const float* hp = h + ((size_t)b * L_DIM + c * CHUNK) * D_DIM + d;
    float s = 0.f;
    #pragma unroll 8
    for (int i = 0; i < CHUNK; ++i) s += hp[(size_t)i * D_DIM];
    csum[tid] = s;
}

// ---------------- Phase 1b: build cs (exclusive prefix, L+1 rows) ----------
__global__ __launch_bounds__(256) void build_cs(const float* __restrict__ h,
                                                const float* __restrict__ csum,
                                                float* __restrict__ cs) {
    int tid = blockIdx.x * 256 + threadIdx.x;   // 65536 total
    int d = tid & 1023;
    int c = (tid >> 10) & 7;
    int b = tid >> 13;
    float p = 0.f;
    for (int cc = 0; cc < c; ++cc)
        p += csum[(b << 13) + (cc << 10) + d];
    const float* hp = h + ((size_t)b * L_DIM + c * CHUNK) * D_DIM + d;
    float* cp = cs + ((size_t)b * (L_DIM + 1) + c * CHUNK) * D_DIM + d;
    if (c == 0) cp[0] = 0.f;
    #pragma unroll 8
    for (int i = 0; i < CHUNK; ++i) {
        p += hp[(size_t)i * D_DIM];
        cp[(size_t)(i + 1) * D_DIM] = p;
    }
}

// ---------------- Phase 2: W -> bf16 ----------------
__global__ __launch_bounds__(256) void wconv(const float* __restrict__ W,
                                             unsigned short* __restrict__ Wbf) {
    int tid = blockIdx.x * 256 + threadIdx.x;   // 131072 total
    const float4* p = (const float4*)(W + (size_t)tid * 8);
    float4 a = p[0], c = p[1];
    us8 o;
    o[0] = f2bf(a.x); o[1] = f2bf(a.y); o[2] = f2bf(a.z); o[3] = f2bf(a.w);
    o[4] = f2bf(c.x); o[5] = f2bf(c.y); o[6] = f2bf(c.z); o[7] = f2bf(c.w);
    *(us8*)&Wbf[(size_t)tid * 8] = o;
}

// ---------------- Phase 3: fused span-gather + GEMM + bias + ReLU ----------
// grid 1536 = 384 bm x 4 bn; 512 threads = 8 waves (2 x 4); tile 128x256, BK=64.
// LDS = As 16KB (single) + Bs 2x32KB (dbuf) = 80KB exactly -> 2 blocks/CU.
// Span metadata lives in registers (each thread only builds its own 2 A-rows).
__global__ __launch_bounds__(512, 4) void fused_gemm(
    const float* __restrict__ cs,
    const int* __restrict__ span_idx,
    const unsigned short* __restrict__ Wbf,
    const float* __restrict__ bias,
    float* __restrict__ out) {
    constexpr int K = D_DIM, N = D_DIM;
    __shared__ __align__(16) unsigned short As[128 * 64];      // 16 KB
    __shared__ __align__(16) unsigned short Bs[2][256 * 64];   // 64 KB

    const int tid = threadIdx.x;
    const int wid = tid >> 6, lane = tid & 63;
    const int widbase = wid << 6;

    // XCD-aware bijective swizzle: 1536 blocks, 192 per XCD; one batch's cs
    // slice (2.1 MB) + Wbf (2 MB) per XCD L2.
    int blk = blockIdx.x;
    int swz = (blk & 7) * 192 + (blk >> 3);
    const int bm = swz >> 2;                  // 0..383
    const int bn = swz & 3;                   // 0..3
    const int rowM = bm * 128;
    const int colN = bn * 256;
    const int b = bm / 48;                    // 48 bm-tiles per batch
    const float* csb = cs + (size_t)b * CSB;

    // per-thread A-build: rows ar0 and ar0+64, col-chunk ac8 (8 floats)
    const int ar0 = tid >> 3;                 // 0..63
    const int ac8 = tid & 7;                  // 0..7
    int2 se0 = ((const int2*)span_idx)[rowM + ar0];
    int2 se1 = ((const int2*)span_idx)[rowM + ar0 + 64];
    int st0 = min(max(se0.x, 0), L_DIM - 1), en0 = min(max(se0.y, 0), L_DIM - 1);
    int st1 = min(max(se1.x, 0), L_DIM - 1), en1 = min(max(se1.y, 0), L_DIM - 1);
    const float inv0 = (st0 <= en0) ? 1.0f / (float)(en0 - st0 + 1) : 0.0f;
    const float inv1 = (st1 <= en1) ? 1.0f / (float)(en1 - st1 + 1) : 0.0f;
    const float* pS0 = csb + (st0 << 10) + ac8 * 8;
    const float* pE0 = csb + ((en0 + 1) << 10) + ac8 * 8;
    const float* pS1 = csb + (st1 << 10) + ac8 * 8;
    const float* pE1 = csb + ((en1 + 1) << 10) + ac8 * 8;
    // swizzled LDS write offsets (bytes); (ar0+64)&7 == ar0&7 so same XOR
    const int wa0 = ar0 * 128 + ((ac8 * 16) ^ ((ar0 & 7) << 4));
    const int wa1 = (ar0 + 64) * 128 + ((ac8 * 16) ^ ((ar0 & 7) << 4));

    const int fr = lane & 15;
    const int kq = lane >> 4;
    const int wr = wid >> 2, wc = wid & 3;

    f32x4 acc[4][4];
    #pragma unroll
    for (int i = 0; i < 4; ++i)
        #pragma unroll
        for (int j = 0; j < 4; ++j) acc[i][j] = (f32x4){0.f, 0.f, 0.f, 0.f};

    float4 eA0, eA1, sA0, sA1, eB0, eB1, sB0, sB1;

#define CS_LOAD(k0v) do { \
        eA0 = *(const float4*)(pE0 + (k0v));     eA1 = *(const float4*)(pE0 + (k0v) + 4); \
        sA0 = *(const float4*)(pS0 + (k0v));     sA1 = *(const float4*)(pS0 + (k0v) + 4); \
        eB0 = *(const float4*)(pE1 + (k0v));     eB1 = *(const float4*)(pE1 + (k0v) + 4); \
        sB0 = *(const float4*)(pS1 + (k0v));     sB1 = *(const float4*)(pS1 + (k0v) + 4); \
    } while (0)

#define A_WRITE() do { \
        us8 o0, o1; \
        o0[0] = bf16b((eA0.x - sA0.x) * inv0); o0[1] = bf16b((eA0.y - sA0.y) * inv0); \
        o0[2] = bf16b((eA0.z - sA0.z) * inv0); o0[3] = bf16b((eA0.w - sA0.w) * inv0); \
        o0[4] = bf16b((eA1.x - sA1.x) * inv0); o0[5] = bf16b((eA1.y - sA1.y) * inv0); \
        o0[6] = bf16b((eA1.z - sA1.z) * inv0); o0[7] = bf16b((eA1.w - sA1.w) * inv0); \
        o1[0] = bf16b((eB0.x - sB0.x) * inv1); o1[1] = bf16b((eB0.y - sB0.y) * inv1); \
        o1[2] = bf16b((eB0.z - sB0.z) * inv1); o1[3] = bf16b((eB0.w - sB0.w) * inv1); \
        o1[4] = bf16b((eB1.x - sB1.x) * inv1); o1[5] = bf16b((eB1.y - sB1.y) * inv1); \
        o1[6] = bf16b((eB1.z - sB1.z) * inv1); o1[7] = bf16b((eB1.w - sB1.w) * inv1); \
        *(us8*)((char*)As + wa0) = o0; \
        *(us8*)((char*)As + wa1) = o1; \
    } while (0)

#define STAGE_B(k0v, bufi) do { \
        _Pragma("unroll") \
        for (int i = 0; i < 4; ++i) { \
            int ci = i * 512 + tid; \
            int rB = ci >> 3, cB = ci & 7; \
            const unsigned short* srcB = Wbf + (size_t)(colN + rB) * K + (k0v) + ((cB ^ (rB & 7)) * 8); \
            __builtin_amdgcn_global_load_lds( \
                (const __attribute__((address_space(1))) void*)srcB, \
                (__attribute__((address_space(3))) void*)&Bs[bufi][(i * 512 + widbase) * 8], \
                16, 0, 0); \
        } \
    } while (0)

#define COMPUTE(bufi) do { \
        _Pragma("unroll") \
        for (int ks = 0; ks < 2; ++ks) { \
            const int kb = ks * 64 + kq * 16; \
            short8 af[4], bq[4]; \
            _Pragma("unroll") \
            for (int i = 0; i < 4; ++i) { \
                int ra = wr * 64 + i * 16 + fr; \
                af[i] = *(const short8*)((const char*)As + ra * 128 + (kb ^ ((ra & 7) << 4))); \
                int rb = wc * 64 + i * 16 + fr; \
                bq[i] = *(const short8*)((const char*)Bs[bufi] + rb * 128 + (kb ^ ((rb & 7) << 4))); \
            } \
            _Pragma("unroll") \
            for (int i = 0; i < 4; ++i) \
                _Pragma("unroll") \
                for (int j = 0; j < 4; ++j) \
                    acc[i][j] = __builtin_amdgcn_mfma_f32_16x16x32_bf16(af[i], bq[j], acc[i][j], 0, 0, 0); \
        } \
    } while (0)

    // prologue: tile 0 into As/Bs[0]; issue Bs[1] after the barrier so its
    // drain lands at bar1 of iter 0 (window = COMPUTE(0)).
    CS_LOAD(0);
    STAGE_B(0, 0);
    A_WRITE();                 // waits its cs loads; glds(0) stay in flight
    __syncthreads();           // drains glds(0); tile 0 ready
    STAGE_B(64, 1);

    for (int t = 0; t < 16; ++t) {
        if (t < 15) CS_LOAD((t + 1) * 64);   // gather next A-chunk to regs
        COMPUTE(t & 1);
        __syncthreads();                     // bar1: drains cs(t+1), glds(t+1) — both had a full COMPUTE window
        if (t < 15) A_WRITE();               // convert + ds_write As(t+1)
        __syncthreads();                     // bar2: vmcnt already 0 → cheap (lgkm only)
        if (t < 14) STAGE_B((t + 2) * 64, t & 1);  // issued last → drains at next bar1
    }

    // epilogue: C/D layout col=lane&15, row=(lane>>4)*4+r  (m89/m91)
    const int m0 = rowM + wr * 64;
    const int n0 = colN + wc * 64;
    float bv[4];
    #pragma unroll
    for (int j = 0; j < 4; ++j) bv[j] = bias[n0 + j * 16 + fr];
    #pragma unroll
    for (int i = 0; i < 4; ++i)
        #pragma unroll
        for (int j = 0; j < 4; ++j)
            #pragma unroll
            for (int r = 0; r < 4; ++r) {
                int m = m0 + i * 16 + kq * 4 + r;
                int n = n0 + j * 16 + fr;
                float v = acc[i][j][r] + bv[j];
                out[(size_t)m * N + n] = v > 0.f ? v : 0.f;
            }
#undef CS_LOAD
#undef A_WRITE
#undef STAGE_B
#undef COMPUTE
}

extern "C" void kernel_launch(void* const* d_in, const int* in_sizes, int n_in,
                              void* d_out, int out_size, void* d_ws, size_t ws_size,
                              hipStream_t stream) {
    const float* h = (const float*)d_in[0];
    const int* span = (const int*)d_in[1];
    const float* W = (const float*)d_in[2];
    const float* bias = (const float*)d_in[3];
    float* out = (float*)d_out;

    char* ws = (char*)d_ws;
    // ws layout (bytes):
    //   cs   : [B][L+1][D] fp32 = 16,809,984  @ 0
    //   Wbf  : [D][D]     bf16 =  2,097,152   @ 16,809,984
    //   csum : [B][8][D]  fp32 =    262,144   @ 18,907,136
    float* cs = (float*)(ws);
    unsigned short* Wbf = (unsigned short*)(ws + 16809984);
    float* csum = (float*)(ws + 18907136);

    chunk_sums<<<256, 256, 0, stream>>>(h, csum);
    build_cs<<<256, 256, 0, stream>>>(h, csum, cs);
    wconv<<<512, 256, 0, stream>>>(W, Wbf);
    fused_gemm<<<1536, 512, 0, stream>>>(cs, span, Wbf, bias, out);
}

// Round 6
// 357.638 us; speedup vs baseline: 1.1438x; 1.0669x over previous
//
#include <hip/hip_runtime.h>
#include <hip/hip_bf16.h>
#include <stdint.h>

#define B_DIM 8
#define L_DIM 512
#define D_DIM 1024
#define S_DIM 6144
#define NCHUNK 8
#define CHUNK (L_DIM / NCHUNK)      // 64
#define CSB (513 * 1024)            // floats per batch in cs ([L+1][D])

typedef __attribute__((ext_vector_type(8))) short short8;
typedef __attribute__((ext_vector_type(4))) float f32x4;
typedef __attribute__((ext_vector_type(8))) unsigned short us8;

__device__ __forceinline__ unsigned short bf16b(float x) {
    __hip_bfloat16 h = __float2bfloat16(x);
    return *reinterpret_cast<unsigned short*>(&h);
}

__device__ __forceinline__ unsigned short f2bf(float f) {
    unsigned int u = __float_as_uint(f);
    u += 0x7FFFu + ((u >> 16) & 1u);
    return (unsigned short)(u >> 16);
}

// ---------------- Phase 1a: per-chunk sums of h over L ----------------
__global__ __launch_bounds__(256) void chunk_sums(const float* __restrict__ h,
                                                  float* __restrict__ csum) {
    int tid = blockIdx.x * 256 + threadIdx.x;   // 65536 total
    int d = tid & 1023;
    int c = (tid >> 10) & 7;
    int b = tid >> 13;
    const float* hp = h + ((size_t)b * L_DIM + c * CHUNK) * D_DIM + d;
    float s = 0.f;
    #pragma unroll 8
    for (int i = 0; i < CHUNK; ++i) s += hp[(size_t)i * D_DIM];
    csum[tid] = s;
}

// ---------------- Phase 1b: build cs (exclusive prefix, L+1 rows) ----------
__global__ __launch_bounds__(256) void build_cs(const float* __restrict__ h,
                                                const float* __restrict__ csum,
                                                float* __restrict__ cs) {
    int tid = blockIdx.x * 256 + threadIdx.x;   // 65536 total
    int d = tid & 1023;
    int c = (tid >> 10) & 7;
    int b = tid >> 13;
    float p = 0.f;
    for (int cc = 0; cc < c; ++cc)
        p += csum[(b << 13) + (cc << 10) + d];
    const float* hp = h + ((size_t)b * L_DIM + c * CHUNK) * D_DIM + d;
    float* cp = cs + ((size_t)b * (L_DIM + 1) + c * CHUNK) * D_DIM + d;
    if (c == 0) cp[0] = 0.f;
    #pragma unroll 8
    for (int i = 0; i < CHUNK; ++i) {
        p += hp[(size_t)i * D_DIM];
        cp[(size_t)(i + 1) * D_DIM] = p;
    }
}

// ---------------- Phase 2: W -> bf16 ----------------
__global__ __launch_bounds__(256) void wconv(const float* __restrict__ W,
                                             unsigned short* __restrict__ Wbf) {
    int tid = blockIdx.x * 256 + threadIdx.x;   // 131072 total
    const float4* p = (const float4*)(W + (size_t)tid * 8);
    float4 a = p[0], c = p[1];
    us8 o;
    o[0] = f2bf(a.x); o[1] = f2bf(a.y); o[2] = f2bf(a.z); o[3] = f2bf(a.w);
    o[4] = f2bf(c.x); o[5] = f2bf(c.y); o[6] = f2bf(c.z); o[7] = f2bf(c.w);
    *(us8*)&Wbf[(size_t)tid * 8] = o;
}

// ---------------- Phase 3: fused span-gather + GEMM + bias + ReLU ----------
// Tile 128x256, BK=64, 8 waves (2x4). As/Bs both double-buffered: 96 KB LDS,
// 1 block/CU (occupancy proven not the lever in r5). Counted-vmcnt schedule:
// ONE raw s_barrier per K-tile; cs loads for A(t+1) stay in flight ACROSS the
// barrier (vmcnt(8), never 0 in main loop); B-glds window = full next tile.
// Manual vmcnt ledger (pinned by asm memory fences + sched_barrier):
//   steady state at pre-barrier wait: outstanding = [GB(t+1) x4, CS(t+2) x8]
//   -> vmcnt(8) drains exactly GB(t+1).
__global__ __launch_bounds__(512, 2) void fused_gemm(
    const float* __restrict__ cs,
    const int* __restrict__ span_idx,
    const unsigned short* __restrict__ Wbf,
    const float* __restrict__ bias,
    float* __restrict__ out) {
    constexpr int K = D_DIM, N = D_DIM;
    __shared__ __align__(16) unsigned short As[2][128 * 64];   // 32 KB
    __shared__ __align__(16) unsigned short Bs[2][256 * 64];   // 64 KB

    const int tid = threadIdx.x;
    const int wid = tid >> 6, lane = tid & 63;
    const int widbase = wid << 6;

    // XCD-aware bijective swizzle: 1536 blocks, 192/XCD; XCD x <-> batch x,
    // so cs slice (2.1 MB) + Wbf (2 MB) live in that XCD's private L2.
    int blk = blockIdx.x;
    int swz = (blk & 7) * 192 + (blk >> 3);
    const int bm = swz >> 2;                  // 0..383
    const int bn = swz & 3;                   // 0..3
    const int rowM = bm * 128;
    const int colN = bn * 256;
    const int b = bm / 48;                    // 48 bm-tiles per batch
    const float* csb = cs + (size_t)b * CSB;

    // per-thread A-build: rows ar0 and ar0+64, col-chunk ac8 (8 floats)
    const int ar0 = tid >> 3;                 // 0..63
    const int ac8 = tid & 7;                  // 0..7
    int2 se0 = ((const int2*)span_idx)[rowM + ar0];
    int2 se1 = ((const int2*)span_idx)[rowM + ar0 + 64];
    int st0 = min(max(se0.x, 0), L_DIM - 1), en0 = min(max(se0.y, 0), L_DIM - 1);
    int st1 = min(max(se1.x, 0), L_DIM - 1), en1 = min(max(se1.y, 0), L_DIM - 1);
    const float inv0 = (st0 <= en0) ? 1.0f / (float)(en0 - st0 + 1) : 0.0f;
    const float inv1 = (st1 <= en1) ? 1.0f / (float)(en1 - st1 + 1) : 0.0f;
    const float* pS0 = csb + (st0 << 10) + ac8 * 8;
    const float* pE0 = csb + ((en0 + 1) << 10) + ac8 * 8;
    const float* pS1 = csb + (st1 << 10) + ac8 * 8;
    const float* pE1 = csb + ((en1 + 1) << 10) + ac8 * 8;
    // swizzled LDS write offsets (bytes); (ar0+64)&7 == ar0&7 so same XOR
    const int wa0 = ar0 * 128 + ((ac8 * 16) ^ ((ar0 & 7) << 4));
    const int wa1 = (ar0 + 64) * 128 + ((ac8 * 16) ^ ((ar0 & 7) << 4));

    const int fr = lane & 15;
    const int kq = lane >> 4;
    const int wr = wid >> 2, wc = wid & 3;

    f32x4 acc[4][4];
    #pragma unroll
    for (int i = 0; i < 4; ++i)
        #pragma unroll
        for (int j = 0; j < 4; ++j) acc[i][j] = (f32x4){0.f, 0.f, 0.f, 0.f};

    float4 eA0, eA1, sA0, sA1, eB0, eB1, sB0, sB1;

#define FENCE() do { asm volatile("" ::: "memory"); \
                     __builtin_amdgcn_sched_barrier(0); } while (0)

#define CS_ISSUE(k0v) do { \
        eA0 = *(const float4*)(pE0 + (k0v));     eA1 = *(const float4*)(pE0 + (k0v) + 4); \
        sA0 = *(const float4*)(pS0 + (k0v));     sA1 = *(const float4*)(pS0 + (k0v) + 4); \
        eB0 = *(const float4*)(pE1 + (k0v));     eB1 = *(const float4*)(pE1 + (k0v) + 4); \
        sB0 = *(const float4*)(pS1 + (k0v));     sB1 = *(const float4*)(pS1 + (k0v) + 4); \
    } while (0)

#define A_CONV_WRITE(bufi) do { \
        us8 o0, o1; \
        o0[0] = bf16b((eA0.x - sA0.x) * inv0); o0[1] = bf16b((eA0.y - sA0.y) * inv0); \
        o0[2] = bf16b((eA0.z - sA0.z) * inv0); o0[3] = bf16b((eA0.w - sA0.w) * inv0); \
        o0[4] = bf16b((eA1.x - sA1.x) * inv0); o0[5] = bf16b((eA1.y - sA1.y) * inv0); \
        o0[6] = bf16b((eA1.z - sA1.z) * inv0); o0[7] = bf16b((eA1.w - sA1.w) * inv0); \
        o1[0] = bf16b((eB0.x - sB0.x) * inv1); o1[1] = bf16b((eB0.y - sB0.y) * inv1); \
        o1[2] = bf16b((eB0.z - sB0.z) * inv1); o1[3] = bf16b((eB0.w - sB0.w) * inv1); \
        o1[4] = bf16b((eB1.x - sB1.x) * inv1); o1[5] = bf16b((eB1.y - sB1.y) * inv1); \
        o1[6] = bf16b((eB1.z - sB1.z) * inv1); o1[7] = bf16b((eB1.w - sB1.w) * inv1); \
        *(us8*)((char*)As[bufi] + wa0) = o0; \
        *(us8*)((char*)As[bufi] + wa1) = o1; \
    } while (0)

#define STAGE_B(k0v, bufi) do { \
        _Pragma("unroll") \
        for (int i = 0; i < 4; ++i) { \
            int ci = i * 512 + tid; \
            int rB = ci >> 3, cB = ci & 7; \
            const unsigned short* srcB = Wbf + (size_t)(colN + rB) * K + (k0v) + ((cB ^ (rB & 7)) * 8); \
            __builtin_amdgcn_global_load_lds( \
                (const __attribute__((address_space(1))) void*)srcB, \
                (__attribute__((address_space(3))) void*)&Bs[bufi][(i * 512 + widbase) * 8], \
                16, 0, 0); \
        } \
    } while (0)

#define COMPUTE(bufi) do { \
        _Pragma("unroll") \
        for (int ks = 0; ks < 2; ++ks) { \
            const int kb = ks * 64 + kq * 16; \
            short8 af[4], bq[4]; \
            _Pragma("unroll") \
            for (int i = 0; i < 4; ++i) { \
                int ra = wr * 64 + i * 16 + fr; \
                af[i] = *(const short8*)((const char*)As[bufi] + ra * 128 + (kb ^ ((ra & 7) << 4))); \
                int rb = wc * 64 + i * 16 + fr; \
                bq[i] = *(const short8*)((const char*)Bs[bufi] + rb * 128 + (kb ^ ((rb & 7) << 4))); \
            } \
            __builtin_amdgcn_s_setprio(1); \
            _Pragma("unroll") \
            for (int i = 0; i < 4; ++i) \
                _Pragma("unroll") \
                for (int j = 0; j < 4; ++j) \
                    acc[i][j] = __builtin_amdgcn_mfma_f32_16x16x32_bf16(af[i], bq[j], acc[i][j], 0, 0, 0); \
            __builtin_amdgcn_s_setprio(0); \
        } \
    } while (0)

    // ---- prologue ----
    // issue order pinned by fences: CS(0) | GB(0) | conv(0) | CS(1) | wait | bar | GB(1)
    CS_ISSUE(0);                  // 8 vmem (oldest)
    FENCE();
    STAGE_B(0, 0);                // +4 glds -> Bs[0]
    FENCE();
    A_CONV_WRITE(0);              // compiler waits CS(0) (vmcnt(4)); writes As[0]
    CS_ISSUE(64);                 // outstanding: [GB0 x4, CS1 x8]
    FENCE();
    asm volatile("s_waitcnt vmcnt(8) lgkmcnt(0)" ::: "memory");  // GB0 done, A0 committed
    __builtin_amdgcn_s_barrier();
    FENCE();
    STAGE_B(64, 1);               // GB(1) -> Bs[1]; outstanding: [CS1 x8, GB1 x4]
    FENCE();

    // ---- main loop: one s_barrier per tile, counted vmcnt ----
    for (int t = 0; t < 16; ++t) {
        const int cur = t & 1;
        COMPUTE(cur);
        if (t < 15) {
            A_CONV_WRITE(cur ^ 1);          // consumes CS(t+1) (compiler vmcnt(4)); ds_write As[nxt]
            if (t < 14) CS_ISSUE((t + 2) * 64);
            FENCE();
            if (t < 14)
                asm volatile("s_waitcnt vmcnt(8) lgkmcnt(0)" ::: "memory");  // GB(t+1) done; CS(t+2) stays in flight
            else
                asm volatile("s_waitcnt vmcnt(0) lgkmcnt(0)" ::: "memory");  // tail: drain GB(15)
            __builtin_amdgcn_s_barrier();
            FENCE();
            if (t < 14) {
                STAGE_B((t + 2) * 64, cur); // GB(t+2) -> Bs[cur]; window = next tile
                FENCE();
            }
        }
    }

    // ---- epilogue: C/D layout col=lane&15, row=(lane>>4)*4+r (m89/m91) ----
    const int m0 = rowM + wr * 64;
    const int n0 = colN + wc * 64;
    float bv[4];
    #pragma unroll
    for (int j = 0; j < 4; ++j) bv[j] = bias[n0 + j * 16 + fr];
    #pragma unroll
    for (int i = 0; i < 4; ++i)
        #pragma unroll
        for (int j = 0; j < 4; ++j)
            #pragma unroll
            for (int r = 0; r < 4; ++r) {
                int m = m0 + i * 16 + kq * 4 + r;
                int n = n0 + j * 16 + fr;
                float v = acc[i][j][r] + bv[j];
                out[(size_t)m * N + n] = v > 0.f ? v : 0.f;
            }
#undef FENCE
#undef CS_ISSUE
#undef A_CONV_WRITE
#undef STAGE_B
#undef COMPUTE
}

extern "C" void kernel_launch(void* const* d_in, const int* in_sizes, int n_in,
                              void* d_out, int out_size, void* d_ws, size_t ws_size,
                              hipStream_t stream) {
    const float* h = (const float*)d_in[0];
    const int* span = (const int*)d_in[1];
    const float* W = (const float*)d_in[2];
    const float* bias = (const float*)d_in[3];
    float* out = (float*)d_out;

    char* ws = (char*)d_ws;
    // ws layout (bytes):
    //   cs   : [B][L+1][D] fp32 = 16,809,984  @ 0
    //   Wbf  : [D][D]     bf16 =  2,097,152   @ 16,809,984
    //   csum : [B][8][D]  fp32 =    262,144   @ 18,907,136
    float* cs = (float*)(ws);
    unsigned short* Wbf = (unsigned short*)(ws + 16809984);
    float* csum = (float*)(ws + 18907136);

    chunk_sums<<<256, 256, 0, stream>>>(h, csum);
    build_cs<<<256, 256, 0, stream>>>(h, csum, cs);
    wconv<<<512, 256, 0, stream>>>(W, Wbf);
    fused_gemm<<<1536, 512, 0, stream>>>(cs, span, Wbf, bias, out);
}